// Round 16
// baseline (430.563 us; speedup 1.0000x reference)
//
#include <hip/hip_runtime.h>
#include <cstddef>
#include <cstdint>

#define NN 50000
#define NE 600000
#define NB 391                    // buckets of 128 dst nodes

typedef __attribute__((ext_vector_type(8))) short bf16x8;
typedef __attribute__((ext_vector_type(4))) float f32x4;

#define SWZ(x) (((x) ^ ((x) >> 2)) & 3)

__device__ __forceinline__ float bf2f(ushort u) {
    return __uint_as_float(((uint32_t)u) << 16);
}
__device__ __forceinline__ ushort f2bf(float f) {   // round-to-nearest-even
    uint32_t b = __float_as_uint(f);
    return (ushort)((b + 0x7FFF + ((b >> 16) & 1)) >> 16);
}

// ---------------------------------------------------------------- weights->bf16 transposed
// Wt[c][k] layouts: wf1[128][32] wf2[128][32] wg[l][128][128] wfg[l][128][256] wl1[128][256]
__global__ __launch_bounds__(256)
void convert_weights(const float* __restrict__ f1W, const float* __restrict__ f2W,
                     const float* __restrict__ gW, const float* __restrict__ fgW,
                     const float* __restrict__ l1W, ushort* __restrict__ wt)
{
    int i = blockIdx.x * 256 + threadIdx.x;          // 0 .. 335871
    if (i >= 335872) return;
    float v;
    if (i < 4096) {                                  // wf1
        int c = i >> 5, k = i & 31;
        v = f1W[k * 128 + c];
    } else if (i < 8192) {                           // wf2
        int j = i - 4096; int c = j >> 5, k = j & 31;
        v = f2W[k * 128 + c];
    } else if (i < 8192 + 98304) {                   // wg
        int j = i - 8192; int l = j >> 14, r = j & 16383;
        int c = r >> 7, k = r & 127;
        v = gW[l * 16384 + k * 128 + c];
    } else if (i < 8192 + 98304 + 196608) {          // wfg
        int j = i - (8192 + 98304); int l = j >> 15, r = j & 32767;
        int c = r >> 8, k = r & 255;
        v = fgW[l * 32768 + k * 128 + c];
    } else {                                         // wl1
        int j = i - (8192 + 98304 + 196608);
        int c = j >> 8, k = j & 255;
        v = l1W[k * 128 + c];
    }
    wt[i] = f2bf(v);
}

// ---------------------------------------------------------------- preproc (out bf16)
__global__ __launch_bounds__(256)
void preproc_kernel(const float* __restrict__ x, const float* __restrict__ W,
                    const float* __restrict__ b, ushort* __restrict__ out)
{
    __shared__ float Wl[512];
    __shared__ float bl[32];
    int tx = threadIdx.x;
    Wl[tx]       = W[tx];
    Wl[tx + 256] = W[tx + 256];
    if (tx < 32) bl[tx] = b[tx];
    __syncthreads();
    int n = blockIdx.x * 256 + tx;
    if (n >= NN) return;
    float xr[16];
    const float4* xp = (const float4*)(x + (size_t)n * 16);
#pragma unroll
    for (int q = 0; q < 4; ++q) {
        float4 v = xp[q];
        xr[q*4+0]=v.x; xr[q*4+1]=v.y; xr[q*4+2]=v.z; xr[q*4+3]=v.w;
    }
    float acc[32];
#pragma unroll
    for (int c = 0; c < 32; ++c) acc[c] = bl[c];
#pragma unroll
    for (int k = 0; k < 16; ++k)
#pragma unroll
        for (int c = 0; c < 32; ++c)
            acc[c] = fmaf(xr[k], Wl[k*32+c], acc[c]);
    ushort4* op = (ushort4*)(out + (size_t)n * 32);
#pragma unroll
    for (int q = 0; q < 8; ++q) {
        ushort4 v;
        v.x = f2bf(fmaxf(acc[q*4+0], 0.f));
        v.y = f2bf(fmaxf(acc[q*4+1], 0.f));
        v.z = f2bf(fmaxf(acc[q*4+2], 0.f));
        v.w = f2bf(fmaxf(acc[q*4+3], 0.f));
        op[q] = v;
    }
}

// ---------------------------------------------------------------- plain MFMA GEMM (fc_in1)
__global__ __launch_bounds__(128)
void gemm_mfma(const ushort* __restrict__ A1, int K1,
               const ushort* __restrict__ Wt, const float* __restrict__ bias,
               ushort* __restrict__ out, int nrows)
{
    __shared__ ushort Atile[64 * 32];
    __shared__ ushort Btile[128 * 32];
    const int tx   = threadIdx.x;
    const int wave = tx >> 6;
    const int lane = tx & 63;
    const int bm   = blockIdx.x * 64;
    const int Ktot = K1;

    const int rs  = lane >> 2;
    const int chn = (lane & 3) ^ SWZ(rs);
    const int m    = lane & 15;
    const int quad = lane >> 4;
    const int slot = quad ^ SWZ(m);

    f32x4 acc0[8], acc1[8];
#pragma unroll
    for (int t = 0; t < 8; ++t) {
        acc0[t] = (f32x4){0.f, 0.f, 0.f, 0.f};
        acc1[t] = (f32x4){0.f, 0.f, 0.f, 0.f};
    }

    for (int kk = 0; kk < Ktot; kk += 32) {
#pragma unroll
        for (int i = 0; i < 2; ++i) {
            int seg = wave + 2 * i;
            int row = seg * 16 + rs;
            int ar  = bm + row; if (ar >= nrows) ar = nrows - 1;
            __builtin_amdgcn_global_load_lds(
                (const __attribute__((address_space(1))) void*)
                    (A1 + (size_t)ar * K1 + kk + chn * 8),
                (__attribute__((address_space(3))) void*)(Atile + seg * 512),
                16, 0, 0);
        }
#pragma unroll
        for (int i = 0; i < 4; ++i) {
            int seg = wave + 2 * i;
            int col = seg * 16 + rs;
            __builtin_amdgcn_global_load_lds(
                (const __attribute__((address_space(1))) void*)
                    (Wt + (size_t)col * Ktot + kk + chn * 8),
                (__attribute__((address_space(3))) void*)(Btile + seg * 512),
                16, 0, 0);
        }
        __syncthreads();
        bf16x8 af0 = *(const bf16x8*)(Atile + (wave * 32 + m) * 32 + slot * 8);
        bf16x8 af1 = *(const bf16x8*)(Atile + (wave * 32 + 16 + m) * 32 + slot * 8);
#pragma unroll
        for (int t = 0; t < 8; ++t) {
            bf16x8 bfr = *(const bf16x8*)(Btile + (t * 16 + m) * 32 + slot * 8);
            acc0[t] = __builtin_amdgcn_mfma_f32_16x16x32_bf16(af0, bfr, acc0[t], 0, 0, 0);
            acc1[t] = __builtin_amdgcn_mfma_f32_16x16x32_bf16(af1, bfr, acc1[t], 0, 0, 0);
        }
        __syncthreads();
    }

#pragma unroll
    for (int half = 0; half < 2; ++half) {
        const int orow0 = bm + wave * 32 + half * 16 + quad * 4;
#pragma unroll
        for (int t = 0; t < 8; ++t) {
            int col = t * 16 + m;
            float bb = bias[col];
            f32x4 a = half ? acc1[t] : acc0[t];
#pragma unroll
            for (int r = 0; r < 4; ++r) {
                int row = orow0 + r;
                if (row < nrows)
                    out[(size_t)row * 128 + col] = f2bf(fmaxf(a[r] + bb, 0.f));
            }
        }
    }
}

// ---------------------------------------------------------------- fused GEMM (64-row)
// X = relu([A1|A2] @ Wt^T + bias)   (64 rows in LDS, swizzled A-layout)
// out_hw = X @ Wg^T                 (K=128, no bias/act). All row-major.
__global__ __launch_bounds__(128)
void gemm_fused(const ushort* __restrict__ A1, int K1,
                const ushort* __restrict__ A2, int K2,
                const ushort* __restrict__ Wt, const float* __restrict__ bias,
                const ushort* __restrict__ Wg,
                ushort* __restrict__ out_hw, int nrows)
{
    __shared__ ushort Atile[64 * 32];
    __shared__ ushort Btile[128 * 32];
    __shared__ ushort Xt[64 * 128];
    const int tx   = threadIdx.x;
    const int wave = tx >> 6;
    const int lane = tx & 63;
    const int bm   = blockIdx.x * 64;
    const int Ktot = K1 + K2;

    const int rs  = lane >> 2;
    const int chn = (lane & 3) ^ SWZ(rs);
    const int m    = lane & 15;
    const int quad = lane >> 4;
    const int slot = quad ^ SWZ(m);

    f32x4 acc0[8], acc1[8];
#pragma unroll
    for (int t = 0; t < 8; ++t) {
        acc0[t] = (f32x4){0.f, 0.f, 0.f, 0.f};
        acc1[t] = (f32x4){0.f, 0.f, 0.f, 0.f};
    }

    // ---- stage 1 ----
    for (int kk = 0; kk < Ktot; kk += 32) {
        const ushort* asrc; int astr, kl;
        if (kk < K1) { asrc = A1; astr = K1; kl = kk; }
        else         { asrc = A2; astr = K2; kl = kk - K1; }
#pragma unroll
        for (int i = 0; i < 2; ++i) {
            int seg = wave + 2 * i;
            int row = seg * 16 + rs;
            int ar  = bm + row; if (ar >= nrows) ar = nrows - 1;
            __builtin_amdgcn_global_load_lds(
                (const __attribute__((address_space(1))) void*)
                    (asrc + (size_t)ar * astr + kl + chn * 8),
                (__attribute__((address_space(3))) void*)(Atile + seg * 512),
                16, 0, 0);
        }
#pragma unroll
        for (int i = 0; i < 4; ++i) {
            int seg = wave + 2 * i;
            int col = seg * 16 + rs;
            __builtin_amdgcn_global_load_lds(
                (const __attribute__((address_space(1))) void*)
                    (Wt + (size_t)col * Ktot + kk + chn * 8),
                (__attribute__((address_space(3))) void*)(Btile + seg * 512),
                16, 0, 0);
        }
        __syncthreads();
        bf16x8 af0 = *(const bf16x8*)(Atile + (wave * 32 + m) * 32 + slot * 8);
        bf16x8 af1 = *(const bf16x8*)(Atile + (wave * 32 + 16 + m) * 32 + slot * 8);
#pragma unroll
        for (int t = 0; t < 8; ++t) {
            bf16x8 bfr = *(const bf16x8*)(Btile + (t * 16 + m) * 32 + slot * 8);
            acc0[t] = __builtin_amdgcn_mfma_f32_16x16x32_bf16(af0, bfr, acc0[t], 0, 0, 0);
            acc1[t] = __builtin_amdgcn_mfma_f32_16x16x32_bf16(af1, bfr, acc1[t], 0, 0, 0);
        }
        __syncthreads();
    }

    // ---- epilogue 1: bias+relu -> Xt (swizzled A-layout), zero acc ----
#pragma unroll
    for (int half = 0; half < 2; ++half) {
        int rbase = wave * 32 + half * 16 + quad * 4;
#pragma unroll
        for (int t = 0; t < 8; ++t) {
            int col = t * 16 + m;
            float bb = bias[col];
            int c32 = col >> 5, within = col & 7, ks = (col >> 3) & 3;
            f32x4 a = half ? acc1[t] : acc0[t];
#pragma unroll
            for (int r = 0; r < 4; ++r) {
                int row = rbase + r;
                int pos = ks ^ SWZ(row & 15);
                Xt[row * 128 + c32 * 32 + pos * 8 + within] =
                    f2bf(fmaxf(a[r] + bb, 0.f));
            }
        }
    }
#pragma unroll
    for (int t = 0; t < 8; ++t) {
        acc0[t] = (f32x4){0.f, 0.f, 0.f, 0.f};
        acc1[t] = (f32x4){0.f, 0.f, 0.f, 0.f};
    }
    __syncthreads();

    // ---- stage 2: out_hw = X @ Wg^T (K=128) ----
    for (int c32 = 0; c32 < 4; ++c32) {
        int kk = c32 * 32;
#pragma unroll
        for (int i = 0; i < 4; ++i) {
            int seg = wave + 2 * i;
            int col = seg * 16 + rs;
            __builtin_amdgcn_global_load_lds(
                (const __attribute__((address_space(1))) void*)
                    (Wg + (size_t)col * 128 + kk + chn * 8),
                (__attribute__((address_space(3))) void*)(Btile + seg * 512),
                16, 0, 0);
        }
        __syncthreads();
        bf16x8 af0 = *(const bf16x8*)(Xt + (wave * 32 + m) * 128 + kk + slot * 8);
        bf16x8 af1 = *(const bf16x8*)(Xt + (wave * 32 + 16 + m) * 128 + kk + slot * 8);
#pragma unroll
        for (int t = 0; t < 8; ++t) {
            bf16x8 bfr = *(const bf16x8*)(Btile + (t * 16 + m) * 32 + slot * 8);
            acc0[t] = __builtin_amdgcn_mfma_f32_16x16x32_bf16(af0, bfr, acc0[t], 0, 0, 0);
            acc1[t] = __builtin_amdgcn_mfma_f32_16x16x32_bf16(af1, bfr, acc1[t], 0, 0, 0);
        }
        __syncthreads();
    }

    // ---- epilogue 2 ----
#pragma unroll
    for (int half = 0; half < 2; ++half) {
        const int orow0 = bm + wave * 32 + half * 16 + quad * 4;
#pragma unroll
        for (int t = 0; t < 8; ++t) {
            int col = t * 16 + m;
            f32x4 a = half ? acc1[t] : acc0[t];
#pragma unroll
            for (int r = 0; r < 4; ++r) {
                int row = orow0 + r;
                if (row < nrows)
                    out_hw[(size_t)row * 128 + col] = f2bf(a[r]);
            }
        }
    }
}

// ---------------------------------------------------------------- last fused
// X = relu(nid@Wfg5_t + agg@Wfg5_b + b5); HH = relu(nid@l1t + X@l1b + l1bias);
// out = sigmoid(HH @ l2W + l2b)  (fp32, direct to d_out)
__global__ __launch_bounds__(128)
void gemm_last(const ushort* __restrict__ nid, const ushort* __restrict__ agg,
               const ushort* __restrict__ Wt, const float* __restrict__ bias5,
               const ushort* __restrict__ Wl1, const float* __restrict__ l1b,
               const float* __restrict__ l2W, const float* __restrict__ l2b,
               float* __restrict__ out, int nrows)
{
    __shared__ ushort Atile[64 * 32];
    __shared__ ushort Btile[128 * 32];
    __shared__ ushort Xt[64 * 128];
    __shared__ float  w2s[256];
    const int tx   = threadIdx.x;
    const int wave = tx >> 6;
    const int lane = tx & 63;
    const int bm   = blockIdx.x * 64;

    w2s[tx]       = l2W[tx];
    w2s[tx + 128] = l2W[tx + 128];

    const int rs  = lane >> 2;
    const int chn = (lane & 3) ^ SWZ(rs);
    const int m    = lane & 15;
    const int quad = lane >> 4;
    const int slot = quad ^ SWZ(m);

    f32x4 acc0[8], acc1[8];
#pragma unroll
    for (int t = 0; t < 8; ++t) {
        acc0[t] = (f32x4){0.f, 0.f, 0.f, 0.f};
        acc1[t] = (f32x4){0.f, 0.f, 0.f, 0.f};
    }

    // ---- stage 1: X = relu(nid@t + agg@b + b5), Ktot=256 ----
    for (int kk = 0; kk < 256; kk += 32) {
        const ushort* asrc; int kl;
        if (kk < 128) { asrc = nid; kl = kk; }
        else          { asrc = agg; kl = kk - 128; }
#pragma unroll
        for (int i = 0; i < 2; ++i) {
            int seg = wave + 2 * i;
            int row = seg * 16 + rs;
            int ar  = bm + row; if (ar >= nrows) ar = nrows - 1;
            __builtin_amdgcn_global_load_lds(
                (const __attribute__((address_space(1))) void*)
                    (asrc + (size_t)ar * 128 + kl + chn * 8),
                (__attribute__((address_space(3))) void*)(Atile + seg * 512),
                16, 0, 0);
        }
#pragma unroll
        for (int i = 0; i < 4; ++i) {
            int seg = wave + 2 * i;
            int col = seg * 16 + rs;
            __builtin_amdgcn_global_load_lds(
                (const __attribute__((address_space(1))) void*)
                    (Wt + (size_t)col * 256 + kk + chn * 8),
                (__attribute__((address_space(3))) void*)(Btile + seg * 512),
                16, 0, 0);
        }
        __syncthreads();
        bf16x8 af0 = *(const bf16x8*)(Atile + (wave * 32 + m) * 32 + slot * 8);
        bf16x8 af1 = *(const bf16x8*)(Atile + (wave * 32 + 16 + m) * 32 + slot * 8);
#pragma unroll
        for (int t = 0; t < 8; ++t) {
            bf16x8 bfr = *(const bf16x8*)(Btile + (t * 16 + m) * 32 + slot * 8);
            acc0[t] = __builtin_amdgcn_mfma_f32_16x16x32_bf16(af0, bfr, acc0[t], 0, 0, 0);
            acc1[t] = __builtin_amdgcn_mfma_f32_16x16x32_bf16(af1, bfr, acc1[t], 0, 0, 0);
        }
        __syncthreads();
    }

    // ---- epilogue 1 -> Xt ----
#pragma unroll
    for (int half = 0; half < 2; ++half) {
        int rbase = wave * 32 + half * 16 + quad * 4;
#pragma unroll
        for (int t = 0; t < 8; ++t) {
            int col = t * 16 + m;
            float bb = bias5[col];
            int c32 = col >> 5, within = col & 7, ks = (col >> 3) & 3;
            f32x4 a = half ? acc1[t] : acc0[t];
#pragma unroll
            for (int r = 0; r < 4; ++r) {
                int row = rbase + r;
                int pos = ks ^ SWZ(row & 15);
                Xt[row * 128 + c32 * 32 + pos * 8 + within] =
                    f2bf(fmaxf(a[r] + bb, 0.f));
            }
        }
    }
#pragma unroll
    for (int t = 0; t < 8; ++t) {
        acc0[t] = (f32x4){0.f, 0.f, 0.f, 0.f};
        acc1[t] = (f32x4){0.f, 0.f, 0.f, 0.f};
    }
    __syncthreads();

    // ---- stage 2: HH = nid@l1t + X@l1b, Ktot=256 ----
    for (int c8 = 0; c8 < 8; ++c8) {
        int kk = c8 * 32;
        if (c8 < 4) {
#pragma unroll
            for (int i = 0; i < 2; ++i) {
                int seg = wave + 2 * i;
                int row = seg * 16 + rs;
                int ar  = bm + row; if (ar >= nrows) ar = nrows - 1;
                __builtin_amdgcn_global_load_lds(
                    (const __attribute__((address_space(1))) void*)
                        (nid + (size_t)ar * 128 + kk + chn * 8),
                    (__attribute__((address_space(3))) void*)(Atile + seg * 512),
                    16, 0, 0);
            }
        }
#pragma unroll
        for (int i = 0; i < 4; ++i) {
            int seg = wave + 2 * i;
            int col = seg * 16 + rs;
            __builtin_amdgcn_global_load_lds(
                (const __attribute__((address_space(1))) void*)
                    (Wl1 + (size_t)col * 256 + kk + chn * 8),
                (__attribute__((address_space(3))) void*)(Btile + seg * 512),
                16, 0, 0);
        }
        __syncthreads();
        bf16x8 af0, af1;
        if (c8 < 4) {
            af0 = *(const bf16x8*)(Atile + (wave * 32 + m) * 32 + slot * 8);
            af1 = *(const bf16x8*)(Atile + (wave * 32 + 16 + m) * 32 + slot * 8);
        } else {
            int ko = (c8 - 4) * 32;
            af0 = *(const bf16x8*)(Xt + (wave * 32 + m) * 128 + ko + slot * 8);
            af1 = *(const bf16x8*)(Xt + (wave * 32 + 16 + m) * 128 + ko + slot * 8);
        }
#pragma unroll
        for (int t = 0; t < 8; ++t) {
            bf16x8 bfr = *(const bf16x8*)(Btile + (t * 16 + m) * 32 + slot * 8);
            acc0[t] = __builtin_amdgcn_mfma_f32_16x16x32_bf16(af0, bfr, acc0[t], 0, 0, 0);
            acc1[t] = __builtin_amdgcn_mfma_f32_16x16x32_bf16(af1, bfr, acc1[t], 0, 0, 0);
        }
        __syncthreads();
    }

    // ---- epilogue: relu(HH+l1b) @ l2W, sigmoid, write fp32 out ----
    float bb[8];
#pragma unroll
    for (int t = 0; t < 8; ++t) bb[t] = l1b[t * 16 + m];
    float b20 = l2b[0], b21 = l2b[1];
#pragma unroll
    for (int half = 0; half < 2; ++half) {
#pragma unroll
        for (int r = 0; r < 4; ++r) {
            float p0 = 0.f, p1 = 0.f;
#pragma unroll
            for (int t = 0; t < 8; ++t) {
                int col = t * 16 + m;
                f32x4 a = half ? acc1[t] : acc0[t];
                float v = fmaxf(a[r] + bb[t], 0.f);
                p0 = fmaf(v, w2s[col * 2 + 0], p0);
                p1 = fmaf(v, w2s[col * 2 + 1], p1);
            }
#pragma unroll
            for (int mask = 1; mask < 16; mask <<= 1) {
                p0 += __shfl_xor(p0, mask);
                p1 += __shfl_xor(p1, mask);
            }
            if (m == 0) {
                int row = bm + wave * 32 + half * 16 + quad * 4 + r;
                if (row < nrows) {
                    out[(size_t)row * 2 + 0] = 1.f / (1.f + __expf(-(p0 + b20)));
                    out[(size_t)row * 2 + 1] = 1.f / (1.f + __expf(-(p1 + b21)));
                }
            }
        }
    }
}

// ---------------------------------------------------------------- CSR build v2
__global__ __launch_bounds__(256)
void bhist_kernel(const int* __restrict__ dst, int* __restrict__ bcnt)
{
    __shared__ int h[NB];
    int tx = threadIdx.x;
    for (int i = tx; i < NB; i += 256) h[i] = 0;
    __syncthreads();
    int e0 = blockIdx.x * 1024;
#pragma unroll
    for (int k = 0; k < 4; ++k) {
        int e = e0 + k * 256 + tx;
        if (e < NE) atomicAdd(&h[dst[e] >> 7], 1);
    }
    __syncthreads();
    for (int i = tx; i < NB; i += 256)
        if (h[i]) atomicAdd(&bcnt[i], h[i]);
}

__global__ __launch_bounds__(512)
void bscan_kernel(const int* __restrict__ bcnt, int* __restrict__ bbase,
                  int* __restrict__ bcur)
{
    __shared__ int buf[512];
    int t = threadIdx.x;
    int v = (t < NB) ? bcnt[t] : 0;
    buf[t] = v;
    __syncthreads();
    for (int s = 1; s < 512; s <<= 1) {
        int u = (t >= s) ? buf[t - s] : 0;
        __syncthreads();
        buf[t] += u;
        __syncthreads();
    }
    if (t < NB) {
        int ex = buf[t] - v;
        bbase[t] = ex;
        bcur[t]  = ex;
    }
    if (t == 0) bbase[NB] = NE;
}

__global__ __launch_bounds__(256)
void pass1_kernel(const int* __restrict__ src, const int* __restrict__ dst,
                  const float* __restrict__ w, int* __restrict__ bcur,
                  unsigned int* __restrict__ stage_pk,
                  unsigned char* __restrict__ stage_dl)
{
    __shared__ int cnt[NB];
    __shared__ int gbase[NB];
    int tx = threadIdx.x;
    for (int i = tx; i < NB; i += 256) cnt[i] = 0;
    __syncthreads();
    int e0 = blockIdx.x * 1024;
    int myd[4], myrank[4];
    unsigned int mypk[4];
#pragma unroll
    for (int k = 0; k < 4; ++k) {
        int e = e0 + k * 256 + tx;
        if (e < NE) {
            int d = dst[e];
            myd[k]    = d;
            mypk[k]   = (unsigned int)src[e] | ((unsigned int)f2bf(w[e]) << 17);
            myrank[k] = atomicAdd(&cnt[d >> 7], 1);
        } else {
            myd[k] = -1;
        }
    }
    __syncthreads();
    for (int i = tx; i < NB; i += 256)
        gbase[i] = cnt[i] ? atomicAdd(&bcur[i], cnt[i]) : 0;
    __syncthreads();
#pragma unroll
    for (int k = 0; k < 4; ++k) {
        if (myd[k] >= 0) {
            int p = gbase[myd[k] >> 7] + myrank[k];
            stage_pk[p] = mypk[k];
            stage_dl[p] = (unsigned char)(myd[k] & 127);
        }
    }
}

__global__ __launch_bounds__(256)
void pass2_kernel(const unsigned int* __restrict__ stage_pk,
                  const unsigned char* __restrict__ stage_dl,
                  const int* __restrict__ bbase,
                  unsigned int* __restrict__ esw, int* __restrict__ off)
{
    __shared__ int h[128];
    __shared__ int lofs[128];
    int b    = blockIdx.x;
    int tx   = threadIdx.x;
    int base = bbase[b];
    int cnt  = bbase[b + 1] - base;
    if (tx < 128) h[tx] = 0;
    __syncthreads();
    for (int i = tx; i < cnt; i += 256)
        atomicAdd(&h[stage_dl[base + i]], 1);
    __syncthreads();
    if (tx == 0) {
        int run = 0;
        for (int i = 0; i < 128; ++i) { lofs[i] = run; run += h[i]; }
    }
    __syncthreads();
    int node0 = b * 128;
    if (tx < 128) {
        int n = node0 + tx;
        if (n < NN) off[n] = base + lofs[tx];
        h[tx] = 0;                       // reset for rank pass
    }
    if (b == NB - 1 && tx == 0) off[NN] = NE;
    __syncthreads();
    for (int i = tx; i < cnt; i += 256) {
        int d = stage_dl[base + i];
        int r = atomicAdd(&h[d], 1);
        esw[base + lofs[d] + r] = stage_pk[base + i];
    }
}

// ---------------------------------------------------------------- gather agg (wave/8 nodes)
// One wave handles 8 consecutive nodes (contiguous dst-sorted esw range,
// staged 64 records/load). Per edge one coalesced full-wave dword row load
// (lane i -> ch 2i,2i+1). 16-deep load pipeline. Node boundaries via
// wave-uniform scalar checks. Pad records pk=0 -> +0.0*row0.
__global__ __launch_bounds__(256)
void gather_agg(const ushort* __restrict__ hw,
                const unsigned int* __restrict__ esw,
                const int* __restrict__ off, const float* __restrict__ gbias,
                ushort* __restrict__ agg)
{
    const int g    = blockIdx.x * 4 + (threadIdx.x >> 6);   // node-group id
    const int lane = threadIdx.x & 63;
    int n = g * 8;
    if (n >= NN) return;
    int n_end = n + 8; if (n_end > NN) n_end = NN;
    const int base = off[n];
    const int end  = off[n_end];
    int nb = off[n + 1];
    const ushort* hp = hw + lane * 2;
    const float g0 = gbias[lane * 2], g1 = gbias[lane * 2 + 1];
    float a0 = 0.f, a1 = 0.f;

    for (int chunk = base; chunk < end; chunk += 64) {
        int idx = chunk + lane;
        int pk = (idx < end) ? (int)esw[idx] : 0;
        int cnt = end - chunk; if (cnt > 64) cnt = 64;
        int cnt16 = (cnt + 15) & ~15;
        for (int j = 0; j < cnt16; j += 16) {
            int pp[16];
            unsigned int rv[16];
#pragma unroll
            for (int k = 0; k < 16; ++k)
                pp[k] = __builtin_amdgcn_readlane(pk, j + k);
#pragma unroll
            for (int k = 0; k < 16; ++k)
                rv[k] = *(const unsigned int*)(hp + (size_t)(pp[k] & 0x1FFFF) * 128);
#pragma unroll
            for (int k = 0; k < 16; ++k) {
                int e = chunk + j + k;
                while (e == nb) {                 // node boundary: flush node n
                    unsigned int o = (unsigned int)f2bf(fmaxf(a0 + g0, 0.f)) |
                                     ((unsigned int)f2bf(fmaxf(a1 + g1, 0.f)) << 16);
                    *(unsigned int*)(agg + (size_t)n * 128 + lane * 2) = o;
                    a0 = 0.f; a1 = 0.f;
                    ++n;
                    nb = (n < n_end) ? off[n + 1] : 0x7fffffff;
                }
                float w = bf2f((ushort)((unsigned int)pp[k] >> 17));
                a0 = fmaf(bf2f((ushort)(rv[k] & 0xffff)), w, a0);
                a1 = fmaf(bf2f((ushort)(rv[k] >> 16)),    w, a1);
            }
        }
    }
    while (n < n_end) {                           // flush remaining nodes
        unsigned int o = (unsigned int)f2bf(fmaxf(a0 + g0, 0.f)) |
                         ((unsigned int)f2bf(fmaxf(a1 + g1, 0.f)) << 16);
        *(unsigned int*)(agg + (size_t)n * 128 + lane * 2) = o;
        a0 = 0.f; a1 = 0.f;
        ++n;
    }
}

// ---------------------------------------------------------------- launch
extern "C" void kernel_launch(void* const* d_in, const int* in_sizes, int n_in,
                              void* d_out, int out_size, void* d_ws, size_t ws_size,
                              hipStream_t stream)
{
    const float* x    = (const float*)d_in[0];
    const int*   esrc = (const int*)  d_in[1];
    const int*   edst = (const int*)  d_in[2];
    const float* ew   = (const float*)d_in[3];
    const float* preW = (const float*)d_in[4];
    const float* preb = (const float*)d_in[5];
    const float* f1W  = (const float*)d_in[6];
    const float* f1b  = (const float*)d_in[7];
    const float* f2W  = (const float*)d_in[8];
    const float* f2b  = (const float*)d_in[9];
    const float* gW   = (const float*)d_in[10];
    const float* gb   = (const float*)d_in[11];
    const float* fgW  = (const float*)d_in[12];
    const float* fgb  = (const float*)d_in[13];
    const float* l1W  = (const float*)d_in[14];
    const float* l1b  = (const float*)d_in[15];
    const float* l2W  = (const float*)d_in[16];
    const float* l2b  = (const float*)d_in[17];
    float* out = (float*)d_out;

    ushort* wt   = (ushort*)d_ws;
    ushort* wf1  = wt;                          //   4096
    ushort* wf2  = wf1 + 4096;                  //   4096
    ushort* wg   = wf2 + 4096;                  //  98304
    ushort* wfg  = wg  + 98304;                 // 196608
    ushort* wl1  = wfg + 196608;                //  32768
    ushort* h0b  = wl1 + 32768;                 // N*32
    ushort* nidb = h0b  + (size_t)NN * 32;      // N*128
    ushort* hwb  = nidb + (size_t)NN * 128;     // N*128 row-major
    ushort* aggb = hwb  + (size_t)NN * 128;     // N*128 row-major
    ushort* endu = aggb + (size_t)NN * 128;
    unsigned int* esw      = (unsigned int*)(((uintptr_t)endu + 15) & ~(uintptr_t)15);
    unsigned int* stage_pk = esw + NE;
    int*          bcnt     = (int*)(stage_pk + NE);   // NB
    int*          bbase    = bcnt + NB + 1;           // NB+1
    int*          bcur     = bbase + NB + 1;          // NB
    int*          off      = bcur + NB + 1;           // NN+1
    unsigned char* stage_dl = (unsigned char*)(off + NN + 2);  // NE bytes

    const int gblocks = (NN + 63) / 64;         // 782
    const int eblocks = (NE + 1023) / 1024;     // 586
    const int ngroups = (NN + 7) / 8;           // 6250
    const int wblocks = (ngroups + 3) / 4;      // 1563 (4 waves/block)

    convert_weights<<<(335872 + 255) / 256, 256, 0, stream>>>(f1W, f2W, gW, fgW, l1W, wt);

    // ---- CSR build v2 (two-level counting sort; reused by all 6 layers) ----
    hipMemsetAsync(bcnt, 0, (size_t)NB * sizeof(int), stream);
    bhist_kernel<<<eblocks, 256, 0, stream>>>(edst, bcnt);
    bscan_kernel<<<1, 512, 0, stream>>>(bcnt, bbase, bcur);
    pass1_kernel<<<eblocks, 256, 0, stream>>>(esrc, edst, ew, bcur, stage_pk, stage_dl);
    pass2_kernel<<<NB, 256, 0, stream>>>(stage_pk, stage_dl, bbase, esw, off);

    // ---- network ----
    preproc_kernel<<<(NN + 255) / 256, 256, 0, stream>>>(x, preW, preb, h0b);
    gemm_mfma<<<gblocks, 128, 0, stream>>>(h0b, 32, wf1, f1b, nidb, NN);
    // fc_in2 + gcn0 : hwb = relu(h0@Wf2+b) @ Wg0
    gemm_fused<<<gblocks, 128, 0, stream>>>(h0b, 32, nullptr, 0, wf2, f2b,
                                            wg, hwb, NN);
    for (int l = 0; l < 6; ++l) {
        gather_agg<<<wblocks, 256, 0, stream>>>(hwb, esw, off,
                                                gb + (size_t)l * 128, aggb);
        if (l < 5) {
            gemm_fused<<<gblocks, 128, 0, stream>>>(nidb, 128, aggb, 128,
                                                    wfg + (size_t)l * 32768,
                                                    fgb + (size_t)l * 128,
                                                    wg + (size_t)(l + 1) * 16384,
                                                    hwb, NN);
        }
    }
    gemm_last<<<gblocks, 128, 0, stream>>>(nidb, aggb,
                                           wfg + (size_t)5 * 32768,
                                           fgb + (size_t)5 * 128,
                                           wl1, l1b, l2W, l2b, out, NN);
}

// Round 17
// 417.136 us; speedup vs baseline: 1.0322x; 1.0322x over previous
//
#include <hip/hip_runtime.h>
#include <cstddef>
#include <cstdint>

#define NN 50000
#define NE 600000
#define NB 391                    // buckets of 128 dst nodes

typedef __attribute__((ext_vector_type(8))) short bf16x8;
typedef __attribute__((ext_vector_type(4))) float f32x4;

#define SWZ(x) (((x) ^ ((x) >> 2)) & 3)

__device__ __forceinline__ float bf2f(ushort u) {
    return __uint_as_float(((uint32_t)u) << 16);
}
__device__ __forceinline__ ushort f2bf(float f) {   // round-to-nearest-even
    uint32_t b = __float_as_uint(f);
    return (ushort)((b + 0x7FFF + ((b >> 16) & 1)) >> 16);
}

// ---------------------------------------------------------------- convert_weights + bhist (merged, independent)
// blocks 0..1311: weights->bf16 transposed; blocks 1312..1897: bucket histogram
__global__ __launch_bounds__(256)
void convbh_kernel(const float* __restrict__ f1W, const float* __restrict__ f2W,
                   const float* __restrict__ gW, const float* __restrict__ fgW,
                   const float* __restrict__ l1W, ushort* __restrict__ wt,
                   const int* __restrict__ dst, int* __restrict__ bcnt)
{
    if (blockIdx.x < 1312) {
        int i = blockIdx.x * 256 + threadIdx.x;          // 0 .. 335871
        if (i >= 335872) return;
        float v;
        if (i < 4096) {                                  // wf1
            int c = i >> 5, k = i & 31;
            v = f1W[k * 128 + c];
        } else if (i < 8192) {                           // wf2
            int j = i - 4096; int c = j >> 5, k = j & 31;
            v = f2W[k * 128 + c];
        } else if (i < 8192 + 98304) {                   // wg
            int j = i - 8192; int l = j >> 14, r = j & 16383;
            int c = r >> 7, k = r & 127;
            v = gW[l * 16384 + k * 128 + c];
        } else if (i < 8192 + 98304 + 196608) {          // wfg
            int j = i - (8192 + 98304); int l = j >> 15, r = j & 32767;
            int c = r >> 8, k = r & 255;
            v = fgW[l * 32768 + k * 128 + c];
        } else {                                         // wl1
            int j = i - (8192 + 98304 + 196608);
            int c = j >> 8, k = j & 255;
            v = l1W[k * 128 + c];
        }
        wt[i] = f2bf(v);
    } else {
        __shared__ int h[NB];
        int tx = threadIdx.x;
        for (int i = tx; i < NB; i += 256) h[i] = 0;
        __syncthreads();
        int e0 = (blockIdx.x - 1312) * 1024;
#pragma unroll
        for (int k = 0; k < 4; ++k) {
            int e = e0 + k * 256 + tx;
            if (e < NE) atomicAdd(&h[dst[e] >> 7], 1);
        }
        __syncthreads();
        for (int i = tx; i < NB; i += 256)
            if (h[i]) atomicAdd(&bcnt[i], h[i]);
    }
}

// ---------------------------------------------------------------- bscan
__global__ __launch_bounds__(512)
void bscan_kernel(const int* __restrict__ bcnt, int* __restrict__ bbase,
                  int* __restrict__ bcur)
{
    __shared__ int buf[512];
    int t = threadIdx.x;
    int v = (t < NB) ? bcnt[t] : 0;
    buf[t] = v;
    __syncthreads();
    for (int s = 1; s < 512; s <<= 1) {
        int u = (t >= s) ? buf[t - s] : 0;
        __syncthreads();
        buf[t] += u;
        __syncthreads();
    }
    if (t < NB) {
        int ex = buf[t] - v;
        bbase[t] = ex;
        bcur[t]  = ex;
    }
    if (t == 0) bbase[NB] = NE;
}

// ---------------------------------------------------------------- pass1
__global__ __launch_bounds__(256)
void pass1_kernel(const int* __restrict__ src, const int* __restrict__ dst,
                  const float* __restrict__ w, int* __restrict__ bcur,
                  unsigned int* __restrict__ stage_pk,
                  unsigned char* __restrict__ stage_dl)
{
    __shared__ int cnt[NB];
    __shared__ int gbase[NB];
    int tx = threadIdx.x;
    for (int i = tx; i < NB; i += 256) cnt[i] = 0;
    __syncthreads();
    int e0 = blockIdx.x * 1024;
    int myd[4], myrank[4];
    unsigned int mypk[4];
#pragma unroll
    for (int k = 0; k < 4; ++k) {
        int e = e0 + k * 256 + tx;
        if (e < NE) {
            int d = dst[e];
            myd[k]    = d;
            mypk[k]   = (unsigned int)src[e] | ((unsigned int)f2bf(w[e]) << 17);
            myrank[k] = atomicAdd(&cnt[d >> 7], 1);
        } else {
            myd[k] = -1;
        }
    }
    __syncthreads();
    for (int i = tx; i < NB; i += 256)
        gbase[i] = cnt[i] ? atomicAdd(&bcur[i], cnt[i]) : 0;
    __syncthreads();
#pragma unroll
    for (int k = 0; k < 4; ++k) {
        if (myd[k] >= 0) {
            int p = gbase[myd[k] >> 7] + myrank[k];
            stage_pk[p] = mypk[k];
            stage_dl[p] = (unsigned char)(myd[k] & 127);
        }
    }
}

// ---------------------------------------------------------------- pass2 + preproc (merged, independent)
// blocks 0..390: within-bucket sort -> esw, off; blocks 391..586: preproc x->h0b
__global__ __launch_bounds__(256)
void p2pre_kernel(const unsigned int* __restrict__ stage_pk,
                  const unsigned char* __restrict__ stage_dl,
                  const int* __restrict__ bbase,
                  unsigned int* __restrict__ esw, int* __restrict__ off,
                  const float* __restrict__ x, const float* __restrict__ preW,
                  const float* __restrict__ preb, ushort* __restrict__ h0b)
{
    if (blockIdx.x < NB) {
        __shared__ int h[128];
        __shared__ int lofs[128];
        int b    = blockIdx.x;
        int tx   = threadIdx.x;
        int base = bbase[b];
        int cnt  = bbase[b + 1] - base;
        if (tx < 128) h[tx] = 0;
        __syncthreads();
        for (int i = tx; i < cnt; i += 256)
            atomicAdd(&h[stage_dl[base + i]], 1);
        __syncthreads();
        if (tx == 0) {
            int run = 0;
            for (int i = 0; i < 128; ++i) { lofs[i] = run; run += h[i]; }
        }
        __syncthreads();
        int node0 = b * 128;
        if (tx < 128) {
            int n = node0 + tx;
            if (n < NN) off[n] = base + lofs[tx];
            h[tx] = 0;                       // reset for rank pass
        }
        if (b == NB - 1 && tx == 0) off[NN] = NE;
        __syncthreads();
        for (int i = tx; i < cnt; i += 256) {
            int d = stage_dl[base + i];
            int r = atomicAdd(&h[d], 1);
            esw[base + lofs[d] + r] = stage_pk[base + i];
        }
    } else {
        __shared__ float Wl[512];
        __shared__ float bl[32];
        int tx = threadIdx.x;
        Wl[tx]       = preW[tx];
        Wl[tx + 256] = preW[tx + 256];
        if (tx < 32) bl[tx] = preb[tx];
        __syncthreads();
        int n = (blockIdx.x - NB) * 256 + tx;
        if (n >= NN) return;
        float xr[16];
        const float4* xp = (const float4*)(x + (size_t)n * 16);
#pragma unroll
        for (int q = 0; q < 4; ++q) {
            float4 v = xp[q];
            xr[q*4+0]=v.x; xr[q*4+1]=v.y; xr[q*4+2]=v.z; xr[q*4+3]=v.w;
        }
        float acc[32];
#pragma unroll
        for (int c = 0; c < 32; ++c) acc[c] = bl[c];
#pragma unroll
        for (int k = 0; k < 16; ++k)
#pragma unroll
            for (int c = 0; c < 32; ++c)
                acc[c] = fmaf(xr[k], Wl[k*32+c], acc[c]);
        ushort4* op = (ushort4*)(h0b + (size_t)n * 32);
#pragma unroll
        for (int q = 0; q < 8; ++q) {
            ushort4 v;
            v.x = f2bf(fmaxf(acc[q*4+0], 0.f));
            v.y = f2bf(fmaxf(acc[q*4+1], 0.f));
            v.z = f2bf(fmaxf(acc[q*4+2], 0.f));
            v.w = f2bf(fmaxf(acc[q*4+3], 0.f));
            op[q] = v;
        }
    }
}

// ---------------------------------------------------------------- fc_in1 + fused layer0 (merged; both read h0b only)
// blocks 0..781: nidb = relu(h0b@wf1+f1b);  blocks 782..1563: hwb = relu(h0b@wf2+f2b)@wg0
__global__ __launch_bounds__(128)
void fc1f0_kernel(const ushort* __restrict__ h0b,
                  const ushort* __restrict__ wf1, const float* __restrict__ f1b,
                  ushort* __restrict__ nidb,
                  const ushort* __restrict__ wf2, const float* __restrict__ f2b,
                  const ushort* __restrict__ wg, ushort* __restrict__ hwb)
{
    __shared__ ushort Atile[64 * 32];
    __shared__ ushort Btile[128 * 32];
    __shared__ ushort Xt[64 * 128];
    const int tx   = threadIdx.x;
    const int wave = tx >> 6;
    const int lane = tx & 63;
    const int rs  = lane >> 2;
    const int chn = (lane & 3) ^ SWZ(rs);
    const int m    = lane & 15;
    const int quad = lane >> 4;
    const int slot = quad ^ SWZ(m);

    if (blockIdx.x < 782) {
        // ---- fc_in1 path (K=32) ----
        const int bm = blockIdx.x * 64;
        f32x4 acc0[8], acc1[8];
#pragma unroll
        for (int t = 0; t < 8; ++t) {
            acc0[t] = (f32x4){0.f, 0.f, 0.f, 0.f};
            acc1[t] = (f32x4){0.f, 0.f, 0.f, 0.f};
        }
#pragma unroll
        for (int i = 0; i < 2; ++i) {
            int seg = wave + 2 * i;
            int row = seg * 16 + rs;
            int ar  = bm + row; if (ar >= NN) ar = NN - 1;
            __builtin_amdgcn_global_load_lds(
                (const __attribute__((address_space(1))) void*)
                    (h0b + (size_t)ar * 32 + chn * 8),
                (__attribute__((address_space(3))) void*)(Atile + seg * 512),
                16, 0, 0);
        }
#pragma unroll
        for (int i = 0; i < 4; ++i) {
            int seg = wave + 2 * i;
            int col = seg * 16 + rs;
            __builtin_amdgcn_global_load_lds(
                (const __attribute__((address_space(1))) void*)
                    (wf1 + (size_t)col * 32 + chn * 8),
                (__attribute__((address_space(3))) void*)(Btile + seg * 512),
                16, 0, 0);
        }
        __syncthreads();
        bf16x8 af0 = *(const bf16x8*)(Atile + (wave * 32 + m) * 32 + slot * 8);
        bf16x8 af1 = *(const bf16x8*)(Atile + (wave * 32 + 16 + m) * 32 + slot * 8);
#pragma unroll
        for (int t = 0; t < 8; ++t) {
            bf16x8 bfr = *(const bf16x8*)(Btile + (t * 16 + m) * 32 + slot * 8);
            acc0[t] = __builtin_amdgcn_mfma_f32_16x16x32_bf16(af0, bfr, acc0[t], 0, 0, 0);
            acc1[t] = __builtin_amdgcn_mfma_f32_16x16x32_bf16(af1, bfr, acc1[t], 0, 0, 0);
        }
        __syncthreads();
#pragma unroll
        for (int half = 0; half < 2; ++half) {
            const int orow0 = bm + wave * 32 + half * 16 + quad * 4;
#pragma unroll
            for (int t = 0; t < 8; ++t) {
                int col = t * 16 + m;
                float bb = f1b[col];
                f32x4 a = half ? acc1[t] : acc0[t];
#pragma unroll
                for (int r = 0; r < 4; ++r) {
                    int row = orow0 + r;
                    if (row < NN)
                        nidb[(size_t)row * 128 + col] = f2bf(fmaxf(a[r] + bb, 0.f));
                }
            }
        }
    } else {
        // ---- fused layer0 path: X = relu(h0b@wf2+f2b); hwb = X@wg0 ----
        const int bm = (blockIdx.x - 782) * 64;
        f32x4 acc0[8], acc1[8];
#pragma unroll
        for (int t = 0; t < 8; ++t) {
            acc0[t] = (f32x4){0.f, 0.f, 0.f, 0.f};
            acc1[t] = (f32x4){0.f, 0.f, 0.f, 0.f};
        }
        // stage 1 (Ktot=32, single chunk)
#pragma unroll
        for (int i = 0; i < 2; ++i) {
            int seg = wave + 2 * i;
            int row = seg * 16 + rs;
            int ar  = bm + row; if (ar >= NN) ar = NN - 1;
            __builtin_amdgcn_global_load_lds(
                (const __attribute__((address_space(1))) void*)
                    (h0b + (size_t)ar * 32 + chn * 8),
                (__attribute__((address_space(3))) void*)(Atile + seg * 512),
                16, 0, 0);
        }
#pragma unroll
        for (int i = 0; i < 4; ++i) {
            int seg = wave + 2 * i;
            int col = seg * 16 + rs;
            __builtin_amdgcn_global_load_lds(
                (const __attribute__((address_space(1))) void*)
                    (wf2 + (size_t)col * 32 + chn * 8),
                (__attribute__((address_space(3))) void*)(Btile + seg * 512),
                16, 0, 0);
        }
        __syncthreads();
        {
            bf16x8 af0 = *(const bf16x8*)(Atile + (wave * 32 + m) * 32 + slot * 8);
            bf16x8 af1 = *(const bf16x8*)(Atile + (wave * 32 + 16 + m) * 32 + slot * 8);
#pragma unroll
            for (int t = 0; t < 8; ++t) {
                bf16x8 bfr = *(const bf16x8*)(Btile + (t * 16 + m) * 32 + slot * 8);
                acc0[t] = __builtin_amdgcn_mfma_f32_16x16x32_bf16(af0, bfr, acc0[t], 0, 0, 0);
                acc1[t] = __builtin_amdgcn_mfma_f32_16x16x32_bf16(af1, bfr, acc1[t], 0, 0, 0);
            }
        }
        __syncthreads();
        // epilogue 1 -> Xt (swizzled A-layout)
#pragma unroll
        for (int half = 0; half < 2; ++half) {
            int rbase = wave * 32 + half * 16 + quad * 4;
#pragma unroll
            for (int t = 0; t < 8; ++t) {
                int col = t * 16 + m;
                float bb = f2b[col];
                int c32 = col >> 5, within = col & 7, ks = (col >> 3) & 3;
                f32x4 a = half ? acc1[t] : acc0[t];
#pragma unroll
                for (int r = 0; r < 4; ++r) {
                    int row = rbase + r;
                    int pos = ks ^ SWZ(row & 15);
                    Xt[row * 128 + c32 * 32 + pos * 8 + within] =
                        f2bf(fmaxf(a[r] + bb, 0.f));
                }
            }
        }
#pragma unroll
        for (int t = 0; t < 8; ++t) {
            acc0[t] = (f32x4){0.f, 0.f, 0.f, 0.f};
            acc1[t] = (f32x4){0.f, 0.f, 0.f, 0.f};
        }
        __syncthreads();
        // stage 2: hwb = X @ wg0^T (K=128)
        for (int c32 = 0; c32 < 4; ++c32) {
            int kk = c32 * 32;
#pragma unroll
            for (int i = 0; i < 4; ++i) {
                int seg = wave + 2 * i;
                int col = seg * 16 + rs;
                __builtin_amdgcn_global_load_lds(
                    (const __attribute__((address_space(1))) void*)
                        (wg + (size_t)col * 128 + kk + chn * 8),
                    (__attribute__((address_space(3))) void*)(Btile + seg * 512),
                    16, 0, 0);
            }
            __syncthreads();
            bf16x8 af0 = *(const bf16x8*)(Xt + (wave * 32 + m) * 128 + kk + slot * 8);
            bf16x8 af1 = *(const bf16x8*)(Xt + (wave * 32 + 16 + m) * 128 + kk + slot * 8);
#pragma unroll
            for (int t = 0; t < 8; ++t) {
                bf16x8 bfr = *(const bf16x8*)(Btile + (t * 16 + m) * 32 + slot * 8);
                acc0[t] = __builtin_amdgcn_mfma_f32_16x16x32_bf16(af0, bfr, acc0[t], 0, 0, 0);
                acc1[t] = __builtin_amdgcn_mfma_f32_16x16x32_bf16(af1, bfr, acc1[t], 0, 0, 0);
            }
            __syncthreads();
        }
#pragma unroll
        for (int half = 0; half < 2; ++half) {
            const int orow0 = bm + wave * 32 + half * 16 + quad * 4;
#pragma unroll
            for (int t = 0; t < 8; ++t) {
                int col = t * 16 + m;
                f32x4 a = half ? acc1[t] : acc0[t];
#pragma unroll
                for (int r = 0; r < 4; ++r) {
                    int row = orow0 + r;
                    if (row < NN)
                        hwb[(size_t)row * 128 + col] = f2bf(a[r]);
                }
            }
        }
    }
}

// ---------------------------------------------------------------- fused GEMM (64-row)
// X = relu([A1|A2] @ Wt^T + bias)   (64 rows in LDS, swizzled A-layout)
// out_hw = X @ Wg^T                 (K=128, no bias/act). All row-major.
__global__ __launch_bounds__(128)
void gemm_fused(const ushort* __restrict__ A1, int K1,
                const ushort* __restrict__ A2, int K2,
                const ushort* __restrict__ Wt, const float* __restrict__ bias,
                const ushort* __restrict__ Wg,
                ushort* __restrict__ out_hw, int nrows)
{
    __shared__ ushort Atile[64 * 32];
    __shared__ ushort Btile[128 * 32];
    __shared__ ushort Xt[64 * 128];
    const int tx   = threadIdx.x;
    const int wave = tx >> 6;
    const int lane = tx & 63;
    const int bm   = blockIdx.x * 64;
    const int Ktot = K1 + K2;

    const int rs  = lane >> 2;
    const int chn = (lane & 3) ^ SWZ(rs);
    const int m    = lane & 15;
    const int quad = lane >> 4;
    const int slot = quad ^ SWZ(m);

    f32x4 acc0[8], acc1[8];
#pragma unroll
    for (int t = 0; t < 8; ++t) {
        acc0[t] = (f32x4){0.f, 0.f, 0.f, 0.f};
        acc1[t] = (f32x4){0.f, 0.f, 0.f, 0.f};
    }

    // ---- stage 1 ----
    for (int kk = 0; kk < Ktot; kk += 32) {
        const ushort* asrc; int astr, kl;
        if (kk < K1) { asrc = A1; astr = K1; kl = kk; }
        else         { asrc = A2; astr = K2; kl = kk - K1; }
#pragma unroll
        for (int i = 0; i < 2; ++i) {
            int seg = wave + 2 * i;
            int row = seg * 16 + rs;
            int ar  = bm + row; if (ar >= nrows) ar = nrows - 1;
            __builtin_amdgcn_global_load_lds(
                (const __attribute__((address_space(1))) void*)
                    (asrc + (size_t)ar * astr + kl + chn * 8),
                (__attribute__((address_space(3))) void*)(Atile + seg * 512),
                16, 0, 0);
        }
#pragma unroll
        for (int i = 0; i < 4; ++i) {
            int seg = wave + 2 * i;
            int col = seg * 16 + rs;
            __builtin_amdgcn_global_load_lds(
                (const __attribute__((address_space(1))) void*)
                    (Wt + (size_t)col * Ktot + kk + chn * 8),
                (__attribute__((address_space(3))) void*)(Btile + seg * 512),
                16, 0, 0);
        }
        __syncthreads();
        bf16x8 af0 = *(const bf16x8*)(Atile + (wave * 32 + m) * 32 + slot * 8);
        bf16x8 af1 = *(const bf16x8*)(Atile + (wave * 32 + 16 + m) * 32 + slot * 8);
#pragma unroll
        for (int t = 0; t < 8; ++t) {
            bf16x8 bfr = *(const bf16x8*)(Btile + (t * 16 + m) * 32 + slot * 8);
            acc0[t] = __builtin_amdgcn_mfma_f32_16x16x32_bf16(af0, bfr, acc0[t], 0, 0, 0);
            acc1[t] = __builtin_amdgcn_mfma_f32_16x16x32_bf16(af1, bfr, acc1[t], 0, 0, 0);
        }
        __syncthreads();
    }

    // ---- epilogue 1: bias+relu -> Xt (swizzled A-layout), zero acc ----
#pragma unroll
    for (int half = 0; half < 2; ++half) {
        int rbase = wave * 32 + half * 16 + quad * 4;
#pragma unroll
        for (int t = 0; t < 8; ++t) {
            int col = t * 16 + m;
            float bb = bias[col];
            int c32 = col >> 5, within = col & 7, ks = (col >> 3) & 3;
            f32x4 a = half ? acc1[t] : acc0[t];
#pragma unroll
            for (int r = 0; r < 4; ++r) {
                int row = rbase + r;
                int pos = ks ^ SWZ(row & 15);
                Xt[row * 128 + c32 * 32 + pos * 8 + within] =
                    f2bf(fmaxf(a[r] + bb, 0.f));
            }
        }
    }
#pragma unroll
    for (int t = 0; t < 8; ++t) {
        acc0[t] = (f32x4){0.f, 0.f, 0.f, 0.f};
        acc1[t] = (f32x4){0.f, 0.f, 0.f, 0.f};
    }
    __syncthreads();

    // ---- stage 2: out_hw = X @ Wg^T (K=128) ----
    for (int c32 = 0; c32 < 4; ++c32) {
        int kk = c32 * 32;
#pragma unroll
        for (int i = 0; i < 4; ++i) {
            int seg = wave + 2 * i;
            int col = seg * 16 + rs;
            __builtin_amdgcn_global_load_lds(
                (const __attribute__((address_space(1))) void*)
                    (Wg + (size_t)col * 128 + kk + chn * 8),
                (__attribute__((address_space(3))) void*)(Btile + seg * 512),
                16, 0, 0);
        }
        __syncthreads();
        bf16x8 af0 = *(const bf16x8*)(Xt + (wave * 32 + m) * 128 + kk + slot * 8);
        bf16x8 af1 = *(const bf16x8*)(Xt + (wave * 32 + 16 + m) * 128 + kk + slot * 8);
#pragma unroll
        for (int t = 0; t < 8; ++t) {
            bf16x8 bfr = *(const bf16x8*)(Btile + (t * 16 + m) * 32 + slot * 8);
            acc0[t] = __builtin_amdgcn_mfma_f32_16x16x32_bf16(af0, bfr, acc0[t], 0, 0, 0);
            acc1[t] = __builtin_amdgcn_mfma_f32_16x16x32_bf16(af1, bfr, acc1[t], 0, 0, 0);
        }
        __syncthreads();
    }

    // ---- epilogue 2 ----
#pragma unroll
    for (int half = 0; half < 2; ++half) {
        const int orow0 = bm + wave * 32 + half * 16 + quad * 4;
#pragma unroll
        for (int t = 0; t < 8; ++t) {
            int col = t * 16 + m;
            f32x4 a = half ? acc1[t] : acc0[t];
#pragma unroll
            for (int r = 0; r < 4; ++r) {
                int row = orow0 + r;
                if (row < nrows)
                    out_hw[(size_t)row * 128 + col] = f2bf(a[r]);
            }
        }
    }
}

// ---------------------------------------------------------------- last fused
// X = relu(nid@Wfg5_t + agg@Wfg5_b + b5); HH = relu(nid@l1t + X@l1b + l1bias);
// out = sigmoid(HH @ l2W + l2b)  (fp32, direct to d_out)
__global__ __launch_bounds__(128)
void gemm_last(const ushort* __restrict__ nid, const ushort* __restrict__ agg,
               const ushort* __restrict__ Wt, const float* __restrict__ bias5,
               const ushort* __restrict__ Wl1, const float* __restrict__ l1b,
               const float* __restrict__ l2W, const float* __restrict__ l2b,
               float* __restrict__ out, int nrows)
{
    __shared__ ushort Atile[64 * 32];
    __shared__ ushort Btile[128 * 32];
    __shared__ ushort Xt[64 * 128];
    __shared__ float  w2s[256];
    const int tx   = threadIdx.x;
    const int wave = tx >> 6;
    const int lane = tx & 63;
    const int bm   = blockIdx.x * 64;

    w2s[tx]       = l2W[tx];
    w2s[tx + 128] = l2W[tx + 128];

    const int rs  = lane >> 2;
    const int chn = (lane & 3) ^ SWZ(rs);
    const int m    = lane & 15;
    const int quad = lane >> 4;
    const int slot = quad ^ SWZ(m);

    f32x4 acc0[8], acc1[8];
#pragma unroll
    for (int t = 0; t < 8; ++t) {
        acc0[t] = (f32x4){0.f, 0.f, 0.f, 0.f};
        acc1[t] = (f32x4){0.f, 0.f, 0.f, 0.f};
    }

    // ---- stage 1: X = relu(nid@t + agg@b + b5), Ktot=256 ----
    for (int kk = 0; kk < 256; kk += 32) {
        const ushort* asrc; int kl;
        if (kk < 128) { asrc = nid; kl = kk; }
        else          { asrc = agg; kl = kk - 128; }
#pragma unroll
        for (int i = 0; i < 2; ++i) {
            int seg = wave + 2 * i;
            int row = seg * 16 + rs;
            int ar  = bm + row; if (ar >= nrows) ar = nrows - 1;
            __builtin_amdgcn_global_load_lds(
                (const __attribute__((address_space(1))) void*)
                    (asrc + (size_t)ar * 128 + kl + chn * 8),
                (__attribute__((address_space(3))) void*)(Atile + seg * 512),
                16, 0, 0);
        }
#pragma unroll
        for (int i = 0; i < 4; ++i) {
            int seg = wave + 2 * i;
            int col = seg * 16 + rs;
            __builtin_amdgcn_global_load_lds(
                (const __attribute__((address_space(1))) void*)
                    (Wt + (size_t)col * 256 + kk + chn * 8),
                (__attribute__((address_space(3))) void*)(Btile + seg * 512),
                16, 0, 0);
        }
        __syncthreads();
        bf16x8 af0 = *(const bf16x8*)(Atile + (wave * 32 + m) * 32 + slot * 8);
        bf16x8 af1 = *(const bf16x8*)(Atile + (wave * 32 + 16 + m) * 32 + slot * 8);
#pragma unroll
        for (int t = 0; t < 8; ++t) {
            bf16x8 bfr = *(const bf16x8*)(Btile + (t * 16 + m) * 32 + slot * 8);
            acc0[t] = __builtin_amdgcn_mfma_f32_16x16x32_bf16(af0, bfr, acc0[t], 0, 0, 0);
            acc1[t] = __builtin_amdgcn_mfma_f32_16x16x32_bf16(af1, bfr, acc1[t], 0, 0, 0);
        }
        __syncthreads();
    }

    // ---- epilogue 1 -> Xt ----
#pragma unroll
    for (int half = 0; half < 2; ++half) {
        int rbase = wave * 32 + half * 16 + quad * 4;
#pragma unroll
        for (int t = 0; t < 8; ++t) {
            int col = t * 16 + m;
            float bb = bias5[col];
            int c32 = col >> 5, within = col & 7, ks = (col >> 3) & 3;
            f32x4 a = half ? acc1[t] : acc0[t];
#pragma unroll
            for (int r = 0; r < 4; ++r) {
                int row = rbase + r;
                int pos = ks ^ SWZ(row & 15);
                Xt[row * 128 + c32 * 32 + pos * 8 + within] =
                    f2bf(fmaxf(a[r] + bb, 0.f));
            }
        }
    }
#pragma unroll
    for (int t = 0; t < 8; ++t) {
        acc0[t] = (f32x4){0.f, 0.f, 0.f, 0.f};
        acc1[t] = (f32x4){0.f, 0.f, 0.f, 0.f};
    }
    __syncthreads();

    // ---- stage 2: HH = nid@l1t + X@l1b, Ktot=256 ----
    for (int c8 = 0; c8 < 8; ++c8) {
        int kk = c8 * 32;
        if (c8 < 4) {
#pragma unroll
            for (int i = 0; i < 2; ++i) {
                int seg = wave + 2 * i;
                int row = seg * 16 + rs;
                int ar  = bm + row; if (ar >= nrows) ar = nrows - 1;
                __builtin_amdgcn_global_load_lds(
                    (const __attribute__((address_space(1))) void*)
                        (nid + (size_t)ar * 128 + kk + chn * 8),
                    (__attribute__((address_space(3))) void*)(Atile + seg * 512),
                    16, 0, 0);
            }
        }
#pragma unroll
        for (int i = 0; i < 4; ++i) {
            int seg = wave + 2 * i;
            int col = seg * 16 + rs;
            __builtin_amdgcn_global_load_lds(
                (const __attribute__((address_space(1))) void*)
                    (Wl1 + (size_t)col * 256 + kk + chn * 8),
                (__attribute__((address_space(3))) void*)(Btile + seg * 512),
                16, 0, 0);
        }
        __syncthreads();
        bf16x8 af0, af1;
        if (c8 < 4) {
            af0 = *(const bf16x8*)(Atile + (wave * 32 + m) * 32 + slot * 8);
            af1 = *(const bf16x8*)(Atile + (wave * 32 + 16 + m) * 32 + slot * 8);
        } else {
            int ko = (c8 - 4) * 32;
            af0 = *(const bf16x8*)(Xt + (wave * 32 + m) * 128 + ko + slot * 8);
            af1 = *(const bf16x8*)(Xt + (wave * 32 + 16 + m) * 128 + ko + slot * 8);
        }
#pragma unroll
        for (int t = 0; t < 8; ++t) {
            bf16x8 bfr = *(const bf16x8*)(Btile + (t * 16 + m) * 32 + slot * 8);
            acc0[t] = __builtin_amdgcn_mfma_f32_16x16x32_bf16(af0, bfr, acc0[t], 0, 0, 0);
            acc1[t] = __builtin_amdgcn_mfma_f32_16x16x32_bf16(af1, bfr, acc1[t], 0, 0, 0);
        }
        __syncthreads();
    }

    // ---- epilogue: relu(HH+l1b) @ l2W, sigmoid, write fp32 out ----
    float bb[8];
#pragma unroll
    for (int t = 0; t < 8; ++t) bb[t] = l1b[t * 16 + m];
    float b20 = l2b[0], b21 = l2b[1];
#pragma unroll
    for (int half = 0; half < 2; ++half) {
#pragma unroll
        for (int r = 0; r < 4; ++r) {
            float p0 = 0.f, p1 = 0.f;
#pragma unroll
            for (int t = 0; t < 8; ++t) {
                int col = t * 16 + m;
                f32x4 a = half ? acc1[t] : acc0[t];
                float v = fmaxf(a[r] + bb[t], 0.f);
                p0 = fmaf(v, w2s[col * 2 + 0], p0);
                p1 = fmaf(v, w2s[col * 2 + 1], p1);
            }
#pragma unroll
            for (int mask = 1; mask < 16; mask <<= 1) {
                p0 += __shfl_xor(p0, mask);
                p1 += __shfl_xor(p1, mask);
            }
            if (m == 0) {
                int row = bm + wave * 32 + half * 16 + quad * 4 + r;
                if (row < nrows) {
                    out[(size_t)row * 2 + 0] = 1.f / (1.f + __expf(-(p0 + b20)));
                    out[(size_t)row * 2 + 1] = 1.f / (1.f + __expf(-(p1 + b21)));
                }
            }
        }
    }
}

// ---------------------------------------------------------------- gather agg (wave/8 nodes)
__global__ __launch_bounds__(256)
void gather_agg(const ushort* __restrict__ hw,
                const unsigned int* __restrict__ esw,
                const int* __restrict__ off, const float* __restrict__ gbias,
                ushort* __restrict__ agg)
{
    const int g    = blockIdx.x * 4 + (threadIdx.x >> 6);   // node-group id
    const int lane = threadIdx.x & 63;
    int n = g * 8;
    if (n >= NN) return;
    int n_end = n + 8; if (n_end > NN) n_end = NN;
    const int base = off[n];
    const int end  = off[n_end];
    int nb = off[n + 1];
    const ushort* hp = hw + lane * 2;
    const float g0 = gbias[lane * 2], g1 = gbias[lane * 2 + 1];
    float a0 = 0.f, a1 = 0.f;

    for (int chunk = base; chunk < end; chunk += 64) {
        int idx = chunk + lane;
        int pk = (idx < end) ? (int)esw[idx] : 0;
        int cnt = end - chunk; if (cnt > 64) cnt = 64;
        int cnt16 = (cnt + 15) & ~15;
        for (int j = 0; j < cnt16; j += 16) {
            int pp[16];
            unsigned int rv[16];
#pragma unroll
            for (int k = 0; k < 16; ++k)
                pp[k] = __builtin_amdgcn_readlane(pk, j + k);
#pragma unroll
            for (int k = 0; k < 16; ++k)
                rv[k] = *(const unsigned int*)(hp + (size_t)(pp[k] & 0x1FFFF) * 128);
#pragma unroll
            for (int k = 0; k < 16; ++k) {
                int e = chunk + j + k;
                while (e == nb) {                 // node boundary: flush node n
                    unsigned int o = (unsigned int)f2bf(fmaxf(a0 + g0, 0.f)) |
                                     ((unsigned int)f2bf(fmaxf(a1 + g1, 0.f)) << 16);
                    *(unsigned int*)(agg + (size_t)n * 128 + lane * 2) = o;
                    a0 = 0.f; a1 = 0.f;
                    ++n;
                    nb = (n < n_end) ? off[n + 1] : 0x7fffffff;
                }
                float w = bf2f((ushort)((unsigned int)pp[k] >> 17));
                a0 = fmaf(bf2f((ushort)(rv[k] & 0xffff)), w, a0);
                a1 = fmaf(bf2f((ushort)(rv[k] >> 16)),    w, a1);
            }
        }
    }
    while (n < n_end) {                           // flush remaining nodes
        unsigned int o = (unsigned int)f2bf(fmaxf(a0 + g0, 0.f)) |
                         ((unsigned int)f2bf(fmaxf(a1 + g1, 0.f)) << 16);
        *(unsigned int*)(agg + (size_t)n * 128 + lane * 2) = o;
        a0 = 0.f; a1 = 0.f;
        ++n;
    }
}

// ---------------------------------------------------------------- launch
extern "C" void kernel_launch(void* const* d_in, const int* in_sizes, int n_in,
                              void* d_out, int out_size, void* d_ws, size_t ws_size,
                              hipStream_t stream)
{
    const float* x    = (const float*)d_in[0];
    const int*   esrc = (const int*)  d_in[1];
    const int*   edst = (const int*)  d_in[2];
    const float* ew   = (const float*)d_in[3];
    const float* preW = (const float*)d_in[4];
    const float* preb = (const float*)d_in[5];
    const float* f1W  = (const float*)d_in[6];
    const float* f1b  = (const float*)d_in[7];
    const float* f2W  = (const float*)d_in[8];
    const float* f2b  = (const float*)d_in[9];
    const float* gW   = (const float*)d_in[10];
    const float* gb   = (const float*)d_in[11];
    const float* fgW  = (const float*)d_in[12];
    const float* fgb  = (const float*)d_in[13];
    const float* l1W  = (const float*)d_in[14];
    const float* l1b  = (const float*)d_in[15];
    const float* l2W  = (const float*)d_in[16];
    const float* l2b  = (const float*)d_in[17];
    float* out = (float*)d_out;

    ushort* wt   = (ushort*)d_ws;
    ushort* wf1  = wt;                          //   4096
    ushort* wf2  = wf1 + 4096;                  //   4096
    ushort* wg   = wf2 + 4096;                  //  98304
    ushort* wfg  = wg  + 98304;                 // 196608
    ushort* wl1  = wfg + 196608;                //  32768
    ushort* h0b  = wl1 + 32768;                 // N*32
    ushort* nidb = h0b  + (size_t)NN * 32;      // N*128
    ushort* hwb  = nidb + (size_t)NN * 128;     // N*128 row-major
    ushort* aggb = hwb  + (size_t)NN * 128;     // N*128 row-major
    ushort* endu = aggb + (size_t)NN * 128;
    unsigned int* esw      = (unsigned int*)(((uintptr_t)endu + 15) & ~(uintptr_t)15);
    unsigned int* stage_pk = esw + NE;
    int*          bcnt     = (int*)(stage_pk + NE);   // NB
    int*          bbase    = bcnt + NB + 1;           // NB+1
    int*          bcur     = bbase + NB + 1;          // NB
    int*          off      = bcur + NB + 1;           // NN+1
    unsigned char* stage_dl = (unsigned char*)(off + NN + 2);  // NE bytes

    const int gblocks = (NN + 63) / 64;         // 782
    const int eblocks = (NE + 1023) / 1024;     // 586
    const int ngroups = (NN + 7) / 8;           // 6250
    const int wblocks = (ngroups + 3) / 4;      // 1563 (4 waves/block)

    // ---- CSR build + preproc + weight conversion (merged where independent) ----
    hipMemsetAsync(bcnt, 0, (size_t)NB * sizeof(int), stream);
    convbh_kernel<<<1312 + eblocks, 256, 0, stream>>>(f1W, f2W, gW, fgW, l1W, wt,
                                                      edst, bcnt);
    bscan_kernel<<<1, 512, 0, stream>>>(bcnt, bbase, bcur);
    pass1_kernel<<<eblocks, 256, 0, stream>>>(esrc, edst, ew, bcur, stage_pk, stage_dl);
    p2pre_kernel<<<NB + (NN + 255) / 256, 256, 0, stream>>>(stage_pk, stage_dl, bbase,
                                                            esw, off, x, preW, preb, h0b);

    // ---- network ----
    fc1f0_kernel<<<2 * gblocks, 128, 0, stream>>>(h0b, wf1, f1b, nidb,
                                                  wf2, f2b, wg, hwb);
    for (int l = 0; l < 6; ++l) {
        gather_agg<<<wblocks, 256, 0, stream>>>(hwb, esw, off,
                                                gb + (size_t)l * 128, aggb);
        if (l < 5) {
            gemm_fused<<<gblocks, 128, 0, stream>>>(nidb, 128, aggb, 128,
                                                    wfg + (size_t)l * 32768,
                                                    fgb + (size_t)l * 128,
                                                    wg + (size_t)(l + 1) * 16384,
                                                    hwb, NN);
        }
    }
    gemm_last<<<gblocks, 128, 0, stream>>>(nidb, aggb,
                                           wfg + (size_t)5 * 32768,
                                           fgb + (size_t)5 * 128,
                                           wl1, l1b, l2W, l2b, out, NN);
}